// Round 1
// baseline (9.763 us; speedup 1.0000x reference)
//
#include <hip/hip_runtime.h>
#include <math.h>

// Reference collapses:
//   d = sqrt( sum_{i,j} ||c_j - c_i||^2 ) = sqrt( 2N*sum|c_i|^2 - 2*|sum c_i|^2 )   [scalar!]
//   W = sum_{i,j} weights[a_i*(a_i+1)/2 + a_j] = sum_{a,b} cnt[a]*cnt[b]*weights[tri(a)+b]
//   out = W/d + bias
// O(N) + O(100^2) work -> single 1024-thread block.

#define NTHREADS 1024
#define N_WAVES (NTHREADS / 64)

constexpr int N_ATOMS   = 4096;
constexpr int MAX_ATOMS = 100;

__device__ __forceinline__ float waveReduceSum(float v) {
#pragma unroll
    for (int off = 32; off > 0; off >>= 1)
        v += __shfl_down(v, off, 64);
    return v;
}

__global__ __launch_bounds__(NTHREADS)
void SimpleEnergyModel_43903155700342_kernel(
        const float* __restrict__ coords,    // [N_ATOMS, 3]
        const int*   __restrict__ atom_ix,   // [N_ATOMS] (harness: int -> int32)
        const float* __restrict__ weights,   // [5050]
        const float* __restrict__ bias,      // [1]
        float*       __restrict__ out)       // [1]
{
    __shared__ float    s_part[N_WAVES][4];   // per-wave {sumsq, sx, sy, sz}
    __shared__ float    s_w[N_WAVES];         // per-wave weight-sum partials
    __shared__ unsigned s_count[MAX_ATOMS];   // atom-index histogram
    __shared__ float    s_cntf[MAX_ATOMS];    // histogram as float

    const int tid  = threadIdx.x;
    const int lane = tid & 63;
    const int wave = tid >> 6;

    // zero histogram
    for (int t = tid; t < MAX_ATOMS; t += NTHREADS) s_count[t] = 0u;
    __syncthreads();

    // ---- Phase A: O(N) coordinate reductions + histogram --------------------
    float sumsq = 0.f, sx = 0.f, sy = 0.f, sz = 0.f;
    for (int i = tid; i < N_ATOMS; i += NTHREADS) {
        const float x = coords[3 * i + 0];
        const float y = coords[3 * i + 1];
        const float z = coords[3 * i + 2];
        sumsq = fmaf(x, x, sumsq);
        sumsq = fmaf(y, y, sumsq);
        sumsq = fmaf(z, z, sumsq);
        sx += x; sy += y; sz += z;
        atomicAdd(&s_count[atom_ix[i]], 1u);   // LDS integer atomic: deterministic
    }
    sumsq = waveReduceSum(sumsq);
    sx    = waveReduceSum(sx);
    sy    = waveReduceSum(sy);
    sz    = waveReduceSum(sz);
    if (lane == 0) {
        s_part[wave][0] = sumsq;
        s_part[wave][1] = sx;
        s_part[wave][2] = sy;
        s_part[wave][3] = sz;
    }
    __syncthreads();

    // histogram -> float
    for (int t = tid; t < MAX_ATOMS; t += NTHREADS) s_cntf[t] = (float)s_count[t];
    __syncthreads();

    // ---- Phase B: W = sum_{a,b} cnt[a]*cnt[b]*weights[a*(a+1)/2 + b] --------
    float wsum = 0.f;
    for (int idx = tid; idx < MAX_ATOMS * MAX_ATOMS; idx += NTHREADS) {
        const int a = idx / MAX_ATOMS;
        const int b = idx - a * MAX_ATOMS;
        const float cc = s_cntf[a] * s_cntf[b];
        wsum = fmaf(cc, weights[(a * (a + 1)) / 2 + b], wsum);
    }
    wsum = waveReduceSum(wsum);
    if (lane == 0) s_w[wave] = wsum;
    __syncthreads();

    // ---- Final scalar on thread 0 -------------------------------------------
    if (tid == 0) {
        float tss = 0.f, tx = 0.f, ty = 0.f, tz = 0.f, tw = 0.f;
#pragma unroll
        for (int w = 0; w < N_WAVES; ++w) {
            tss += s_part[w][0];
            tx  += s_part[w][1];
            ty  += s_part[w][2];
            tz  += s_part[w][3];
            tw  += s_w[w];
        }
        const float S = 2.f * (float)N_ATOMS * tss - 2.f * (tx * tx + ty * ty + tz * tz);
        const float d = sqrtf(S);
        // reference: nan_to_num(1/d, nan=0) — d>0 here, 1/d finite.
        const float rd = (d != 0.f) ? (1.f / d) : 0.f;
        out[0] = tw * rd + bias[0];
    }
}

extern "C" void kernel_launch(void* const* d_in, const int* in_sizes, int n_in,
                              void* d_out, int out_size, void* d_ws, size_t ws_size,
                              hipStream_t stream) {
    const float* coords  = (const float*)d_in[0];
    const int*   atom_ix = (const int*)  d_in[1];
    const float* weights = (const float*)d_in[2];
    const float* bias    = (const float*)d_in[3];
    float*       out     = (float*)d_out;

    SimpleEnergyModel_43903155700342_kernel<<<1, NTHREADS, 0, stream>>>(
        coords, atom_ix, weights, bias, out);
}

// Round 2
// 9.696 us; speedup vs baseline: 1.0069x; 1.0069x over previous
//
#include <hip/hip_runtime.h>
#include <math.h>

// Reference collapses to scalars:
//   S = sum_{i,j} ||c_j - c_i||^2 = 2N*sum|c_i|^2 - 2*|sum c_i|^2
//   W = sum_{a,b in [0,100)^2} cnt[a]*cnt[b]*weights[a(a+1)/2 + b]
//   out = W / sqrt(S) + bias
// Single 1024-thread block; all long-latency loads issued at kernel entry.

#define NTHREADS 1024
#define N_WAVES (NTHREADS / 64)

constexpr int N_ATOMS   = 4096;
constexpr int MAX_ATOMS = 100;
constexpr int NPAIRS    = MAX_ATOMS * MAX_ATOMS;   // 10000

__device__ __forceinline__ float waveReduceSum(float v) {
#pragma unroll
    for (int off = 32; off > 0; off >>= 1)
        v += __shfl_down(v, off, 64);
    return v;
}

__global__ __launch_bounds__(NTHREADS)
void SimpleEnergyModel_43903155700342_kernel(
        const float* __restrict__ coords,    // [4096, 3]
        const int*   __restrict__ atom_ix,   // [4096] (int32 from harness)
        const float* __restrict__ weights,   // [5050]
        const float* __restrict__ bias,      // [1]
        float*       __restrict__ out)       // [1]
{
    __shared__ float    s_part[N_WAVES][4];   // per-wave {sumsq, sx, sy, sz}
    __shared__ float    s_w[N_WAVES];         // per-wave weight partials
    __shared__ unsigned s_count[MAX_ATOMS];   // atom-index histogram

    const int tid  = threadIdx.x;
    const int lane = tid & 63;
    const int wave = tid >> 6;

    // ---- Early-issue ALL independent global loads (latency hides under A) --
    const float bias0 = bias[0];

    // Pair-weight gather over the 100x100 grid: pair p -> (a=p/100, b=p%100),
    // weight index a(a+1)/2 + b. 10 pairs/thread, fully unrolled -> registers.
    float wv[10];
    int   wa[10], wb[10];
#pragma unroll
    for (int u = 0; u < 10; ++u) {
        const int p = tid + u * NTHREADS;
        if (p < NPAIRS) {
            const int a = p / MAX_ATOMS;
            const int b = p - a * MAX_ATOMS;
            wa[u] = a; wb[u] = b;
            wv[u] = weights[(a * (a + 1)) / 2 + b];
        } else {
            wa[u] = 0; wb[u] = 0; wv[u] = 0.f;   // contributes cc*0 = 0
        }
    }

    // Coords as float4: 12288 floats = 3072 float4 = 3/thread.
    const float4* c4 = (const float4*)coords;
    const float4 v0 = c4[tid];
    const float4 v1 = c4[tid + NTHREADS];
    const float4 v2 = c4[tid + 2 * NTHREADS];

    // Atom indices as int4: 4096 ints = 1024 int4 = 1/thread.
    const int4 ai = ((const int4*)atom_ix)[tid];

    // ---- Histogram (LDS integer atomics: deterministic) --------------------
    if (tid < MAX_ATOMS) s_count[tid] = 0u;
    __syncthreads();
    atomicAdd(&s_count[ai.x], 1u);
    atomicAdd(&s_count[ai.y], 1u);
    atomicAdd(&s_count[ai.z], 1u);
    atomicAdd(&s_count[ai.w], 1u);

    // ---- Coordinate reductions ---------------------------------------------
    // Element at flat index e is component (e % 3) of some atom. A float4 at
    // base e0 (r = e0 % 3) has components: x->r, y->(r+1)%3, z->(r+2)%3, w->r.
    float sumsq = 0.f, c0 = 0.f, c1 = 0.f, c2 = 0.f;
#pragma unroll
    for (int u = 0; u < 3; ++u) {
        const float4 v = (u == 0) ? v0 : (u == 1) ? v1 : v2;
        // base = 4*(tid + 1024*u); 4%3==1, 1024%3==1 -> r = (tid + u) % 3
        const int r = (tid + u) % 3;
        sumsq = fmaf(v.x, v.x, sumsq);
        sumsq = fmaf(v.y, v.y, sumsq);
        sumsq = fmaf(v.z, v.z, sumsq);
        sumsq = fmaf(v.w, v.w, sumsq);
        const float xw = v.x + v.w;
        c0 += (r == 0) ? xw  : ((r == 1) ? v.z : v.y);
        c1 += (r == 0) ? v.y : ((r == 1) ? xw  : v.z);
        c2 += (r == 0) ? v.z : ((r == 1) ? v.y : xw);
    }
    sumsq = waveReduceSum(sumsq);
    c0    = waveReduceSum(c0);
    c1    = waveReduceSum(c1);
    c2    = waveReduceSum(c2);
    if (lane == 0) {
        s_part[wave][0] = sumsq;
        s_part[wave][1] = c0;
        s_part[wave][2] = c1;
        s_part[wave][3] = c2;
    }
    __syncthreads();   // histogram + s_part complete

    // ---- Phase B: W from histogram + preloaded weights ---------------------
    float wsum = 0.f;
#pragma unroll
    for (int u = 0; u < 10; ++u) {
        const float cc = (float)s_count[wa[u]] * (float)s_count[wb[u]];
        wsum = fmaf(cc, wv[u], wsum);
    }
    wsum = waveReduceSum(wsum);
    if (lane == 0) s_w[wave] = wsum;
    __syncthreads();

    // ---- Final: wave 0 reduces the 16 per-wave partials --------------------
    if (wave == 0) {
        float ts = 0.f, tx = 0.f, ty = 0.f, tz = 0.f, tw = 0.f;
        if (lane < N_WAVES) {
            ts = s_part[lane][0];
            tx = s_part[lane][1];
            ty = s_part[lane][2];
            tz = s_part[lane][3];
            tw = s_w[lane];
        }
#pragma unroll
        for (int off = 8; off >= 1; off >>= 1) {
            ts += __shfl_down(ts, off, 64);
            tx += __shfl_down(tx, off, 64);
            ty += __shfl_down(ty, off, 64);
            tz += __shfl_down(tz, off, 64);
            tw += __shfl_down(tw, off, 64);
        }
        if (lane == 0) {
            const float S = 2.f * (float)N_ATOMS * ts - 2.f * (tx * tx + ty * ty + tz * tz);
            const float d = sqrtf(S);
            const float rd = (d != 0.f) ? (1.f / d) : 0.f;  // nan_to_num(1/d)
            out[0] = tw * rd + bias0;
        }
    }
}

extern "C" void kernel_launch(void* const* d_in, const int* in_sizes, int n_in,
                              void* d_out, int out_size, void* d_ws, size_t ws_size,
                              hipStream_t stream) {
    const float* coords  = (const float*)d_in[0];
    const int*   atom_ix = (const int*)  d_in[1];
    const float* weights = (const float*)d_in[2];
    const float* bias    = (const float*)d_in[3];
    float*       out     = (float*)d_out;

    SimpleEnergyModel_43903155700342_kernel<<<1, NTHREADS, 0, stream>>>(
        coords, atom_ix, weights, bias, out);
}